// Round 7
// baseline (553.568 us; speedup 1.0000x reference)
//
#include <hip/hip_runtime.h>
#include <hip/hip_bf16.h>
#include <cstdint>

#define B_   32
#define CIN  12
#define L_   1024
#define T_   64
#define C1_  64
#define C2_  128
#define K_   7
#define PAD_ 3

typedef __attribute__((ext_vector_type(8))) short short8;
typedef __attribute__((ext_vector_type(4))) float float4v;

// ---- workspace layout (bytes) ----
// s1T : bf16 [B][L][half(2)][T][32]  = 268,435,456   (c1 PERMUTED within each 32: pos = kq*8+e*4+r)
// w2hi: bf16 A-frag-linear            = 114,688
// w1f : bf16 A-frag-linear [cp2][ks4][mf4][lane64][j8] = 32,768
// pool: f32  [B][C2]                  = 16,384   (fused avg-pool accumulator, zeroed by K0a)
// zp  : 4,096 B zero page (OOB halo rows for K2's global_load_lds staging)
#define WS_S1T   0ull
#define WS_W2HI  268435456ull
#define WS_W1F   (WS_W2HI + 114688ull)
#define WS_POOL  (WS_W1F + 32768ull)
#define WS_ZP    (WS_POOL + 16384ull)

// global_load_lds: LDS dest is wave-uniform base + lane*16 (linear); global src is
// per-lane (pre-swizzled). size must be a literal 16.
#define GLOAD_LDS(SRC, DST)                                                        \
    __builtin_amdgcn_global_load_lds(                                              \
        (const __attribute__((address_space(1))) unsigned int*)(const void*)(SRC), \
        (__attribute__((address_space(3))) unsigned int*)(void*)(DST), 16, 0, 0)

static __device__ __forceinline__ ushort bf16_hi(float f) {
    __hip_bfloat16 h = __float2bfloat16(f);
    ushort u; __builtin_memcpy(&u, &h, 2); return u;
}
static __device__ __forceinline__ float bf16_back(ushort u) {
    __hip_bfloat16 h; __builtin_memcpy(&h, &u, 2); return __bfloat162float(h);
}

// ---------------- K0a: w2 -> bf16, A-fragment-linear layout (+ zero pool & zero page) ----------------
__global__ __launch_bounds__(256) void k0_prep_w2(const float* __restrict__ w2,
                                                  ushort* __restrict__ w2hi,
                                                  float* __restrict__ pool,
                                                  ushort* __restrict__ zp) {
    int i = blockIdx.x * 256 + threadIdx.x;
    if (i < B_ * C2_) pool[i] = 0.0f;            // stream-ordered before K2's atomics
    if (i < 2048) zp[i] = 0;                     // 4KB zero page for K2 DMA staging
    if (i >= C2_ * K_ * C1_) return;
    int c2 = i / (K_ * C1_);
    int r_ = i % (K_ * C1_);
    int kk = r_ / C1_;
    int c1 = r_ % C1_;
    float w = w2[(c2 * C1_ + c1) * K_ + kk];
    ushort uh = bf16_hi(w);
    int h    = c1 >> 5;
    int c1r  = c1 & 31;
    int e    = c1r >> 4;
    int kq   = (c1r >> 2) & 3;
    int rr   = c1r & 3;
    int j    = e * 4 + rr;
    int mt   = c2 >> 4;
    int lane = kq * 16 + (c2 & 15);
    int o    = ((((kk * 2 + h) * 8 + mt) * 64) + lane) * 8 + j;
    w2hi[o] = uh;
}

// ---------------- K0b: w1 -> bf16 hi/lo, A-fragment-linear for conv1 MFMA ----------------
__global__ __launch_bounds__(256) void k0_prep_w1(const float* __restrict__ w1,
                                                  ushort* __restrict__ w1f) {
    int i = blockIdx.x * 256 + threadIdx.x;      // [cp2][ks4][mf4][lane64][j8] = 16384
    if (i >= 16384) return;
    int j    = i & 7;
    int lane = (i >> 3) & 63;
    int mf   = (i >> 9) & 3;
    int ks   = (i >> 11) & 3;
    int cp   = i >> 13;
    int k    = ks * 32 + (lane >> 4) * 8 + j;
    int dl   = k >> 4;
    int slot = k & 15;
    int c1   = mf * 16 + (lane & 15);
    float v  = (slot < CIN && dl < K_) ? w1[(c1 * CIN + slot) * K_ + dl] : 0.0f;
    ushort hi = bf16_hi(v);
    float  rem = v - bf16_back(hi);
    ushort lo = bf16_hi(rem);
    w1f[i] = cp ? lo : hi;
}

// ---------------- K1: conv1 via bf16 MFMA (hi/lo split) + LIF1 spike -> s1t ----------------
// R7: 8-l consolidation (the R6 k2 win, applied here). 512 threads / 8 waves, wave =
// one l x all 64 c1 (acc[4][4], ~120 unified regs). Stage rows/l 2.5 -> 1.75 (14 rows
// per 8 l), barriers/l halved, LDS 57,344 B -> 2 blocks/CU = 16 waves/CU = 4/SIMD
// (vs 3 blocks x 4 waves = 3/SIMD before). launch_bounds(512,4) caps regs at 128.
// Inner loop and epilogue identical to the R1-verified version.
__global__ __launch_bounds__(512, 4) void k1_conv1_mfma(const float* __restrict__ x,
                                                        const ushort* __restrict__ w1f,
                                                        const float* __restrict__ b1,
                                                        ushort* __restrict__ s1t) {
    __shared__ __align__(16) ushort S[14 * 2048];    // 57,344 B
    int tid  = threadIdx.x;
    int lane = tid & 63;
    int wl   = tid >> 6;                             // 0..7: wave owns l = lb + wl
    int b    = blockIdx.y;
    int bx   = blockIdx.x;
    int swz  = ((bx & 7) << 4) | (bx >> 3);          // XCD swizzle, bijective (128 = 8*16)
    int lb   = swz * 8;

    #pragma unroll
    for (int it = 0; it < 4; ++it) {
        int u = it * 512 + tid;                      // 14*2*64 = 1792 tasks
        if (u < 1792) {
            int t  = u & 63;
            int h2 = (u >> 6) & 1;
            int lp = u >> 7;                         // 0..13
            int gl = lb + lp - PAD_;
            bool ok = (gl >= 0) && (gl < L_);
            short8 hv, lv;
            #pragma unroll
            for (int jj = 0; jj < 8; ++jj) {
                int cin = h2 * 8 + jj;
                float v = (ok && cin < CIN)
                    ? x[(((size_t)b * CIN + cin) * L_ + gl) * T_ + t] : 0.0f;
                ushort hb = bf16_hi(v);
                ushort lo = bf16_hi(v - bf16_back(hb));
                hv[jj] = (short)hb;
                lv[jj] = (short)lo;
            }
            int nt = t >> 4, t15 = t & 15;
            int base = lp * 2048 + nt * 256 + h2 * 128 + t15 * 8;
            *(short8*)&S[base]        = hv;          // cp=0 (hi)
            *(short8*)&S[base + 1024] = lv;          // cp=1 (lo)
        }
    }
    __syncthreads();

    int t15 = lane & 15;
    int h2l = (lane >> 4) & 1;
    int kqh = lane >> 5;

    float4v acc[4][4];                               // constant indices ONLY
    #pragma unroll
    for (int i = 0; i < 4; ++i)
        #pragma unroll
        for (int jn = 0; jn < 4; ++jn)
            acc[i][jn] = (float4v){0.0f, 0.0f, 0.0f, 0.0f};

    #pragma unroll
    for (int ks = 0; ks < 4; ++ks) {
        int dtap = ks * 2 + kqh;
        int lpr  = (dtap == 7) ? 0 : (wl + dtap);    // dl==7: A is zero, row 0 is finite
        int rb   = lpr * 2048 + h2l * 128 + t15 * 8;
        short8 bh[4], bl[4];
        #pragma unroll
        for (int nt = 0; nt < 4; ++nt) {
            bh[nt] = *(const short8*)&S[rb + nt * 256];
            bl[nt] = *(const short8*)&S[rb + nt * 256 + 1024];
        }
        #pragma unroll
        for (int mf = 0; mf < 4; ++mf) {
            const ushort* ap = w1f + ((size_t)(ks * 4 + mf) * 64 + lane) * 8;
            short8 ah = *(const short8*)ap;
            short8 al = *(const short8*)(ap + 8192);     // cp=1 half
            #pragma unroll
            for (int nt = 0; nt < 4; ++nt) {
                acc[mf][nt] = __builtin_amdgcn_mfma_f32_16x16x32_bf16(ah, bh[nt], acc[mf][nt], 0, 0, 0);
                acc[mf][nt] = __builtin_amdgcn_mfma_f32_16x16x32_bf16(al, bh[nt], acc[mf][nt], 0, 0, 0);
                acc[mf][nt] = __builtin_amdgcn_mfma_f32_16x16x32_bf16(ah, bl[nt], acc[mf][nt], 0, 0, 0);
            }
        }
    }

    // spike <=> conv + b1 >= TH1/GAIN = 0.25 (LIF1 tau=1 is memoryless).
    int l  = lb + wl;
    int kq = lane >> 4;
    #pragma unroll
    for (int h = 0; h < 2; ++h) {
        float4v be0 = *(const float4v*)&b1[h * 32 + kq * 4];
        float4v be1 = *(const float4v*)&b1[h * 32 + 16 + kq * 4];
        #pragma unroll
        for (int nt = 0; nt < 4; ++nt) {
            uint s0 = (acc[2 * h][nt][0] + be0[0] >= 0.25f) ? 0x3F80u : 0u;
            uint s1 = (acc[2 * h][nt][1] + be0[1] >= 0.25f) ? 0x3F80u : 0u;
            uint s2 = (acc[2 * h][nt][2] + be0[2] >= 0.25f) ? 0x3F80u : 0u;
            uint s3 = (acc[2 * h][nt][3] + be0[3] >= 0.25f) ? 0x3F80u : 0u;
            uint s4 = (acc[2 * h + 1][nt][0] + be1[0] >= 0.25f) ? 0x3F80u : 0u;
            uint s5 = (acc[2 * h + 1][nt][1] + be1[1] >= 0.25f) ? 0x3F80u : 0u;
            uint s6 = (acc[2 * h + 1][nt][2] + be1[2] >= 0.25f) ? 0x3F80u : 0u;
            uint s7 = (acc[2 * h + 1][nt][3] + be1[3] >= 0.25f) ? 0x3F80u : 0u;
            uint4 u4 = { s0 | (s1 << 16), s2 | (s3 << 16),
                         s4 | (s5 << 16), s6 | (s7 << 16) };
            size_t off = ((((size_t)b * L_ + l) * 2 + h) * T_ + (nt * 16 + t15)) * 32 + kq * 8;
            *(uint4*)&s1t[off] = u4;
        }
    }
}

// ---------------- K2: conv2 (bf16 MFMA) + fused LIF2 + fused avg-pool ----------------
// R7: staging via global_load_lds DMA (m97/m173 pattern). LDS layout is unchanged;
// the (t15,kq) transpose moves into the per-lane GLOBAL source address:
//   LDS chunk D = nt*64 + kq*16 + t15  must hold  global chunk G = nt*64 + t15*4 + kq
//   -> lane i of nt-instruction reads src ushort off = nt*512 + (i&15)*32 + (i>>4)*8.
// OOB halo rows read the 4KB zero page. Removes 2560 ds_writes + 16 staging VGPRs per
// block; __syncthreads()'s vmcnt(0) drain is the completion wait. Rest identical to R6.
// INVARIANT: acc[][] indexed with compile-time constants ONLY (scratch-demotion hazard).
__global__ __launch_bounds__(512, 2) void k2_conv2_lif(const ushort* __restrict__ s1t,
                                                       const ushort* __restrict__ w2hi,
                                                       const float* __restrict__ b2,
                                                       float* __restrict__ pool,
                                                       const ushort* __restrict__ zp) {
    __shared__ __align__(16) unsigned char lds_raw[40960];
    ushort* S = (ushort*)lds_raw;   // stage: [lp10][nt4][kq4][t15 16][j8] = 40,960 B (one h)
    int tid    = threadIdx.x;
    int wv     = tid >> 6;          // 0..7
    int lane   = tid & 63;
    int wn     = wv >> 1;           // l offset 0..3: l = lb + wn
    int wm     = wv & 1;            // m half: c2 in [wm*64, wm*64+64)
    int b      = blockIdx.y;
    int bx     = blockIdx.x;
    int swz    = ((bx & 7) << 5) | (bx >> 3);   // bijective XCD swizzle (256 = 8*32)
    int lb     = swz * 4;
    int lane15 = lane & 15;
    int kq     = lane >> 4;
    int srcoff = lane15 * 32 + (lane >> 4) * 8; // pre-swizzled DMA source (ushorts)

    float4v acc[4][4];             // [m-frag][n-frag], 64 regs — constant indices ONLY
    #pragma unroll
    for (int i = 0; i < 4; ++i)
        #pragma unroll
        for (int j = 0; j < 4; ++j)
            acc[i][j] = (float4v){0.0f, 0.0f, 0.0f, 0.0f};

    #pragma unroll 1
    for (int h = 0; h < 2; ++h) {
        __syncthreads();           // S reads of previous h done
        // DMA stage: rows lb-3..lb+6 (10 x 4KB); wave-uniform row loop, 4 insts/row
        #pragma unroll
        for (int r0 = 0; r0 < 2; ++r0) {
            int r = r0 * 8 + wv;
            if (r < 10) {
                int gl = lb + r - PAD_;
                const ushort* srow = (gl >= 0 && gl < L_)
                    ? &s1t[(((size_t)b * L_ + gl) * 2 + h) * 2048] : zp;
                const ushort* s = srow + srcoff;
                ushort* d = &S[r * 2048];
                GLOAD_LDS(s,        d);
                GLOAD_LDS(s + 512,  d + 512);
                GLOAD_LDS(s + 1024, d + 1024);
                GLOAD_LDS(s + 1536, d + 1536);
            }
        }
        __syncthreads();           // emits vmcnt(0) drain: DMA complete for all waves
        #pragma unroll 2
        for (int kk = 0; kk < K_; ++kk) {
            int lp = wn + kk;            // staged row feeding output l = lb+wn at tap kk
            short8 bf[4];
            #pragma unroll
            for (int nt = 0; nt < 4; ++nt)   // lane-linear 2KB frag -> conflict-free b128
                bf[nt] = *(const short8*)&S[lp * 2048 + nt * 512 + lane * 8];
            #pragma unroll
            for (int mf = 0; mf < 4; ++mf) {
                int aoff = (((kk * 2 + h) * 8 + wm * 4 + mf) * 64 + lane) * 8;  // 32-bit
                short8 ahi = *(const short8*)&w2hi[aoff];
                #pragma unroll
                for (int nt = 0; nt < 4; ++nt)
                    acc[mf][nt] = __builtin_amdgcn_mfma_f32_16x16x32_bf16(ahi, bf[nt], acc[mf][nt], 0, 0, 0);
            }
        }
    }
    __syncthreads();    // all S reads done before epilogue overlays the region

    // ---- epilogue: streaming transpose (one nt = 16 t-rows at a time) + LIF2 scan ----
    // E[t15 16][68]: b128 stores slot=(lane15+kq+4mfl)%8 -> 8 lanes/slot, conflict-free;
    // reads bank (4t+lane)%32 -> 2-way (free). All 64 lanes scan (c2 = wm*64 + lane).
    // Scan: v' = A*v + (E*Cs + D), A = 1-1/0.9, Cs = 2/0.9, D = bias*2/0.9.
    // 8 waves x 4,352 B = 34,816 B overlaid on the 40,960 B stage region.
    float* E = ((float*)lds_raw) + wv * 1088;
    int c2v = wm * 64 + lane;
    const float Af = 1.0f - 1.0f / 0.9f;
    const float Cs = 2.0f / 0.9f;
    float D = b2[c2v] * Cs;
    float v = 0.0f;
    uint cnt = 0u;
    #pragma unroll
    for (int nt = 0; nt < 4; ++nt) {
        *(float4v*)&E[lane15 * 68 + 0 * 16 + kq * 4] = acc[0][nt];   // D: col t = nt*16+lane15
        *(float4v*)&E[lane15 * 68 + 1 * 16 + kq * 4] = acc[1][nt];   //    row c2l = mfl*16+kq*4+r
        *(float4v*)&E[lane15 * 68 + 2 * 16 + kq * 4] = acc[2][nt];
        *(float4v*)&E[lane15 * 68 + 3 * 16 + kq * 4] = acc[3][nt];
        __builtin_amdgcn_s_waitcnt(0);           // wave-local LDS RAW
        #pragma unroll
        for (int tt = 0; tt < 16; ++tt) {
            float e = fmaf(E[tt * 68 + lane], Cs, D);
            v = fmaf(Af, v, e);
            bool sp = (v >= 0.5f);
            cnt += sp ? 1u : 0u;
            v = sp ? 0.0f : v;
        }
        __builtin_amdgcn_s_waitcnt(0);           // reads done before next nt overwrites
    }
    atomicAdd(&pool[b * C2_ + c2v], (float)cnt);  // integer-valued: exact, order-free
}

// ---------------- K3: fc on pooled [B][C2] (pool already summed over l,t) ----------------
__global__ __launch_bounds__(128) void k3_fc(const float* __restrict__ pool,
                                             const float* __restrict__ fcw,
                                             const float* __restrict__ fcb,
                                             float* __restrict__ out) {
    int i = threadIdx.x;          // 128 = B*4 outputs
    int b = i >> 2, c = i & 3;
    float o = fcb[c];
    #pragma unroll 8
    for (int c2 = 0; c2 < C2_; ++c2)
        o = fmaf(fcw[c * C2_ + c2], pool[b * C2_ + c2] * (1.0f / 65536.0f), o);
    out[b * 4 + c] = o;
}

extern "C" void kernel_launch(void* const* d_in, const int* in_sizes, int n_in,
                              void* d_out, int out_size, void* d_ws, size_t ws_size,
                              hipStream_t stream) {
    const float* x   = (const float*)d_in[0];
    const float* w1  = (const float*)d_in[1];
    const float* b1  = (const float*)d_in[2];
    const float* w2  = (const float*)d_in[3];
    const float* b2  = (const float*)d_in[4];
    const float* fcw = (const float*)d_in[5];
    const float* fcb = (const float*)d_in[6];
    float* out = (float*)d_out;

    char* ws = (char*)d_ws;
    ushort* s1t  = (ushort*)(ws + WS_S1T);
    ushort* w2h  = (ushort*)(ws + WS_W2HI);
    ushort* w1f  = (ushort*)(ws + WS_W1F);
    float*  pool = (float*)(ws + WS_POOL);
    ushort* zp   = (ushort*)(ws + WS_ZP);

    k0_prep_w2<<<dim3((C2_ * K_ * C1_ + 255) / 256), dim3(256), 0, stream>>>(w2, w2h, pool, zp);
    k0_prep_w1<<<dim3(64), dim3(256), 0, stream>>>(w1, w1f);
    k1_conv1_mfma<<<dim3(L_ / 8, B_), dim3(512), 0, stream>>>(x, w1f, b1, s1t);
    k2_conv2_lif<<<dim3(L_ / 4, B_), dim3(512), 0, stream>>>(s1t, w2h, b2, pool, zp);
    k3_fc<<<dim3(1), dim3(128), 0, stream>>>(pool, fcw, fcb, out);
}

// Round 8
// 547.907 us; speedup vs baseline: 1.0103x; 1.0103x over previous
//
#include <hip/hip_runtime.h>
#include <hip/hip_bf16.h>
#include <cstdint>

#define B_   32
#define CIN  12
#define L_   1024
#define T_   64
#define C1_  64
#define C2_  128
#define K_   7
#define PAD_ 3

typedef __attribute__((ext_vector_type(8))) short short8;
typedef __attribute__((ext_vector_type(4))) float float4v;

// ---- workspace layout (bytes) ----
// s1T : bf16 [B][L][half(2)][T][32]  = 268,435,456   (c1 PERMUTED within each 32: pos = kq*8+e*4+r)
// w2hi: bf16 A-frag-linear            = 114,688
// w1f : bf16 A-frag-linear [cp2][ks4][mf4][lane64][j8] = 32,768
// pool: f32  [B][C2]                  = 16,384   (fused avg-pool accumulator, zeroed by K0a)
// zp  : 4,096 B zero page (OOB halo rows for K2's global_load_lds staging)
#define WS_S1T   0ull
#define WS_W2HI  268435456ull
#define WS_W1F   (WS_W2HI + 114688ull)
#define WS_POOL  (WS_W1F + 32768ull)
#define WS_ZP    (WS_POOL + 16384ull)

// global_load_lds: LDS dest is wave-uniform base + lane*16 (linear); global src is
// per-lane (pre-swizzled). size must be a literal 16.
#define GLOAD_LDS(SRC, DST)                                                        \
    __builtin_amdgcn_global_load_lds(                                              \
        (const __attribute__((address_space(1))) unsigned int*)(const void*)(SRC), \
        (__attribute__((address_space(3))) unsigned int*)(void*)(DST), 16, 0, 0)

static __device__ __forceinline__ ushort bf16_hi(float f) {
    __hip_bfloat16 h = __float2bfloat16(f);
    ushort u; __builtin_memcpy(&u, &h, 2); return u;
}
static __device__ __forceinline__ float bf16_back(ushort u) {
    __hip_bfloat16 h; __builtin_memcpy(&h, &u, 2); return __bfloat162float(h);
}

// ---------------- K0a: w2 -> bf16, A-fragment-linear layout (+ zero pool & zero page) ----------------
__global__ __launch_bounds__(256) void k0_prep_w2(const float* __restrict__ w2,
                                                  ushort* __restrict__ w2hi,
                                                  float* __restrict__ pool,
                                                  ushort* __restrict__ zp) {
    int i = blockIdx.x * 256 + threadIdx.x;
    if (i < B_ * C2_) pool[i] = 0.0f;            // stream-ordered before K2's atomics
    if (i < 2048) zp[i] = 0;                     // 4KB zero page for K2 DMA staging
    if (i >= C2_ * K_ * C1_) return;
    int c2 = i / (K_ * C1_);
    int r_ = i % (K_ * C1_);
    int kk = r_ / C1_;
    int c1 = r_ % C1_;
    float w = w2[(c2 * C1_ + c1) * K_ + kk];
    ushort uh = bf16_hi(w);
    int h    = c1 >> 5;
    int c1r  = c1 & 31;
    int e    = c1r >> 4;
    int kq   = (c1r >> 2) & 3;
    int rr   = c1r & 3;
    int j    = e * 4 + rr;
    int mt   = c2 >> 4;
    int lane = kq * 16 + (c2 & 15);
    int o    = ((((kk * 2 + h) * 8 + mt) * 64) + lane) * 8 + j;
    w2hi[o] = uh;
}

// ---------------- K0b: w1 -> bf16 hi/lo, A-fragment-linear for conv1 MFMA ----------------
__global__ __launch_bounds__(256) void k0_prep_w1(const float* __restrict__ w1,
                                                  ushort* __restrict__ w1f) {
    int i = blockIdx.x * 256 + threadIdx.x;      // [cp2][ks4][mf4][lane64][j8] = 16384
    if (i >= 16384) return;
    int j    = i & 7;
    int lane = (i >> 3) & 63;
    int mf   = (i >> 9) & 3;
    int ks   = (i >> 11) & 3;
    int cp   = i >> 13;
    int k    = ks * 32 + (lane >> 4) * 8 + j;
    int dl   = k >> 4;
    int slot = k & 15;
    int c1   = mf * 16 + (lane & 15);
    float v  = (slot < CIN && dl < K_) ? w1[(c1 * CIN + slot) * K_ + dl] : 0.0f;
    ushort hi = bf16_hi(v);
    float  rem = v - bf16_back(hi);
    ushort lo = bf16_hi(rem);
    w1f[i] = cp ? lo : hi;
}

// ---------------- K1: conv1 via bf16 MFMA (hi/lo split) + LIF1 spike -> s1t ----------------
// R8: reverted to the R6/R1-proven 256-thread shape (R7's 8-l/512-thread variant cost
// ~29 us — reg-cap/occupancy tradeoff went the wrong way). 4 waves, wave = one l.
__global__ __launch_bounds__(256, 2) void k1_conv1_mfma(const float* __restrict__ x,
                                                        const ushort* __restrict__ w1f,
                                                        const float* __restrict__ b1,
                                                        ushort* __restrict__ s1t) {
    __shared__ __align__(16) ushort S[10 * 2048];    // 40,960 B
    int tid  = threadIdx.x;
    int lane = tid & 63;
    int wl   = tid >> 6;
    int b    = blockIdx.y;
    int bx   = blockIdx.x;
    int swz  = ((bx & 7) << 5) | (bx >> 3);          // XCD swizzle, bijective (256 = 8*32)
    int lb   = swz * 4;

    #pragma unroll
    for (int it = 0; it < 5; ++it) {
        int u  = it * 256 + tid;                     // 10*2*64 = 1280 exactly
        int t  = u & 63;
        int h2 = (u >> 6) & 1;
        int lp = u >> 7;
        int gl = lb + lp - PAD_;
        bool ok = (gl >= 0) && (gl < L_);
        short8 hv, lv;
        #pragma unroll
        for (int jj = 0; jj < 8; ++jj) {
            int cin = h2 * 8 + jj;
            float v = (ok && cin < CIN)
                ? x[(((size_t)b * CIN + cin) * L_ + gl) * T_ + t] : 0.0f;
            ushort hb = bf16_hi(v);
            ushort lo = bf16_hi(v - bf16_back(hb));
            hv[jj] = (short)hb;
            lv[jj] = (short)lo;
        }
        int nt = t >> 4, t15 = t & 15;
        int base = lp * 2048 + nt * 256 + h2 * 128 + t15 * 8;
        *(short8*)&S[base]        = hv;              // cp=0 (hi)
        *(short8*)&S[base + 1024] = lv;              // cp=1 (lo)
    }
    __syncthreads();

    int t15 = lane & 15;
    int h2l = (lane >> 4) & 1;
    int kqh = lane >> 5;

    float4v acc[4][4];                               // constant indices ONLY
    #pragma unroll
    for (int i = 0; i < 4; ++i)
        #pragma unroll
        for (int jn = 0; jn < 4; ++jn)
            acc[i][jn] = (float4v){0.0f, 0.0f, 0.0f, 0.0f};

    #pragma unroll
    for (int ks = 0; ks < 4; ++ks) {
        int dtap = ks * 2 + kqh;
        int lpr  = (dtap == 7) ? 0 : (wl + dtap);    // dl==7: A is zero, row 0 is finite
        int rb   = lpr * 2048 + h2l * 128 + t15 * 8;
        short8 bh[4], bl[4];
        #pragma unroll
        for (int nt = 0; nt < 4; ++nt) {
            bh[nt] = *(const short8*)&S[rb + nt * 256];
            bl[nt] = *(const short8*)&S[rb + nt * 256 + 1024];
        }
        #pragma unroll
        for (int mf = 0; mf < 4; ++mf) {
            const ushort* ap = w1f + ((size_t)(ks * 4 + mf) * 64 + lane) * 8;
            short8 ah = *(const short8*)ap;
            short8 al = *(const short8*)(ap + 8192);     // cp=1 half
            #pragma unroll
            for (int nt = 0; nt < 4; ++nt) {
                acc[mf][nt] = __builtin_amdgcn_mfma_f32_16x16x32_bf16(ah, bh[nt], acc[mf][nt], 0, 0, 0);
                acc[mf][nt] = __builtin_amdgcn_mfma_f32_16x16x32_bf16(al, bh[nt], acc[mf][nt], 0, 0, 0);
                acc[mf][nt] = __builtin_amdgcn_mfma_f32_16x16x32_bf16(ah, bl[nt], acc[mf][nt], 0, 0, 0);
            }
        }
    }

    // spike <=> conv + b1 >= TH1/GAIN = 0.25 (LIF1 tau=1 is memoryless).
    int l  = lb + wl;
    int kq = lane >> 4;
    #pragma unroll
    for (int h = 0; h < 2; ++h) {
        float4v be0 = *(const float4v*)&b1[h * 32 + kq * 4];
        float4v be1 = *(const float4v*)&b1[h * 32 + 16 + kq * 4];
        #pragma unroll
        for (int nt = 0; nt < 4; ++nt) {
            uint s0 = (acc[2 * h][nt][0] + be0[0] >= 0.25f) ? 0x3F80u : 0u;
            uint s1 = (acc[2 * h][nt][1] + be0[1] >= 0.25f) ? 0x3F80u : 0u;
            uint s2 = (acc[2 * h][nt][2] + be0[2] >= 0.25f) ? 0x3F80u : 0u;
            uint s3 = (acc[2 * h][nt][3] + be0[3] >= 0.25f) ? 0x3F80u : 0u;
            uint s4 = (acc[2 * h + 1][nt][0] + be1[0] >= 0.25f) ? 0x3F80u : 0u;
            uint s5 = (acc[2 * h + 1][nt][1] + be1[1] >= 0.25f) ? 0x3F80u : 0u;
            uint s6 = (acc[2 * h + 1][nt][2] + be1[2] >= 0.25f) ? 0x3F80u : 0u;
            uint s7 = (acc[2 * h + 1][nt][3] + be1[3] >= 0.25f) ? 0x3F80u : 0u;
            uint4 u4 = { s0 | (s1 << 16), s2 | (s3 << 16),
                         s4 | (s5 << 16), s6 | (s7 << 16) };
            size_t off = ((((size_t)b * L_ + l) * 2 + h) * T_ + (nt * 16 + t15)) * 32 + kq * 8;
            *(uint4*)&s1t[off] = u4;
        }
    }
}

// ---------------- K2: conv2 (bf16 MFMA) + fused LIF2 + fused avg-pool ----------------
// R8: double-buffered DMA staging with COUNTED vmcnt (T3/T4-lite). Each wave issues
// exactly 5 global_load_lds per buffer (10 rows x 4 chunks / 8 waves). Sequence:
//   issue(buf0,h0); issue(buf1,h1); vmcnt(5)+barrier; compute(h0);
//   vmcnt(0)+barrier; compute(h1); epilogue (no final barrier: E overlays buf0,
//   compute(h1) reads buf1 — disjoint).
// h1's stage flight hides under h0's ~1120-cycle MFMA block; barriers 4 -> 2 per block;
// no __syncthreads full-drain ever stalls the prefetch. Per-wave vmcnt accounting is
// exact (5 own loads per buffer, FIFO retirement). LDS 81,920 B dynamic -> 2 blocks/CU
// (reg-capped at 16 waves/CU regardless). R4/R5 lesson honored: no register staging.
// INVARIANT: acc[][] indexed with compile-time constants ONLY (scratch-demotion hazard).
#define K2_ISSUE(BUF, H) do {                                                     \
    _Pragma("unroll")                                                             \
    for (int i_ = 0; i_ < 5; ++i_) {                                              \
        int q_ = wv * 5 + i_;                                                     \
        int r_ = q_ >> 2, c_ = q_ & 3;                                            \
        int gl_ = lb + r_ - PAD_;                                                 \
        const ushort* srow_ = (gl_ >= 0 && gl_ < L_)                              \
            ? &s1t[(((size_t)b * L_ + gl_) * 2 + (H)) * 2048] : zp;               \
        GLOAD_LDS(srow_ + c_ * 512 + srcoff, Sb + (BUF) * 20480 + r_ * 2048 + c_ * 512); \
    } } while (0)

#define K2_COMPUTE(BUF, H) do {                                                   \
    _Pragma("unroll 2")                                                           \
    for (int kk = 0; kk < K_; ++kk) {                                             \
        int lp = wn + kk;                                                         \
        short8 bf[4];                                                             \
        _Pragma("unroll")                                                         \
        for (int nt = 0; nt < 4; ++nt)   /* lane-linear 2KB frag: conflict-free */\
            bf[nt] = *(const short8*)&Sb[(BUF) * 20480 + lp * 2048 + nt * 512 + lane * 8]; \
        _Pragma("unroll")                                                         \
        for (int mf = 0; mf < 4; ++mf) {                                          \
            int aoff = (((kk * 2 + (H)) * 8 + wm * 4 + mf) * 64 + lane) * 8;      \
            short8 ahi = *(const short8*)&w2hi[aoff];                             \
            _Pragma("unroll")                                                     \
            for (int nt = 0; nt < 4; ++nt)                                        \
                acc[mf][nt] = __builtin_amdgcn_mfma_f32_16x16x32_bf16(ahi, bf[nt], acc[mf][nt], 0, 0, 0); \
        }                                                                         \
    } } while (0)

__global__ __launch_bounds__(512, 2) void k2_conv2_lif(const ushort* __restrict__ s1t,
                                                       const ushort* __restrict__ w2hi,
                                                       const float* __restrict__ b2,
                                                       float* __restrict__ pool,
                                                       const ushort* __restrict__ zp) {
    extern __shared__ __align__(16) unsigned char lds_raw[];   // 81,920 B (2 x 40,960)
    ushort* Sb = (ushort*)lds_raw;
    int tid    = threadIdx.x;
    int wv     = tid >> 6;          // 0..7
    int lane   = tid & 63;
    int wn     = wv >> 1;           // l offset 0..3: l = lb + wn
    int wm     = wv & 1;            // m half: c2 in [wm*64, wm*64+64)
    int b      = blockIdx.y;
    int bx     = blockIdx.x;
    int swz    = ((bx & 7) << 5) | (bx >> 3);   // bijective XCD swizzle (256 = 8*32)
    int lb     = swz * 4;
    int lane15 = lane & 15;
    int kq     = lane >> 4;
    int srcoff = lane15 * 32 + (lane >> 4) * 8; // pre-swizzled DMA source (ushorts)

    float4v acc[4][4];             // [m-frag][n-frag], 64 regs — constant indices ONLY
    #pragma unroll
    for (int i = 0; i < 4; ++i)
        #pragma unroll
        for (int j = 0; j < 4; ++j)
            acc[i][j] = (float4v){0.0f, 0.0f, 0.0f, 0.0f};

    K2_ISSUE(0, 0);                                   // buf0 <- h=0 (5 loads)
    K2_ISSUE(1, 1);                                   // buf1 <- h=1 (5 more in flight)
    asm volatile("s_waitcnt vmcnt(5)" ::: "memory");  // own buf0 loads retired
    __builtin_amdgcn_s_barrier();                     // all waves' buf0 complete
    K2_COMPUTE(0, 0);                                 // h=0 (buf1 DMA flies underneath)
    asm volatile("s_waitcnt vmcnt(0)" ::: "memory");  // own buf1 loads retired
    __builtin_amdgcn_s_barrier();                     // all waves' buf1 complete
    K2_COMPUTE(1, 1);                                 // h=1

    // ---- epilogue: streaming transpose (one nt = 16 t-rows at a time) + LIF2 scan ----
    // E[t15 16][68] per wave overlays buf0 (first 34,816 B); compute(h1) reads buf1
    // only -> no barrier needed. b128 stores conflict-free; reads 2-way (free).
    // Scan: v' = A*v + (E*Cs + D), A = 1-1/0.9, Cs = 2/0.9, D = bias*2/0.9.
    float* E = ((float*)lds_raw) + wv * 1088;
    int c2v = wm * 64 + lane;
    const float Af = 1.0f - 1.0f / 0.9f;
    const float Cs = 2.0f / 0.9f;
    float D = b2[c2v] * Cs;
    float v = 0.0f;
    uint cnt = 0u;
    #pragma unroll
    for (int nt = 0; nt < 4; ++nt) {
        *(float4v*)&E[lane15 * 68 + 0 * 16 + kq * 4] = acc[0][nt];   // D: col t = nt*16+lane15
        *(float4v*)&E[lane15 * 68 + 1 * 16 + kq * 4] = acc[1][nt];   //    row c2l = mfl*16+kq*4+r
        *(float4v*)&E[lane15 * 68 + 2 * 16 + kq * 4] = acc[2][nt];
        *(float4v*)&E[lane15 * 68 + 3 * 16 + kq * 4] = acc[3][nt];
        __builtin_amdgcn_s_waitcnt(0);           // wave-local LDS RAW
        #pragma unroll
        for (int tt = 0; tt < 16; ++tt) {
            float e = fmaf(E[tt * 68 + lane], Cs, D);
            v = fmaf(Af, v, e);
            bool sp = (v >= 0.5f);
            cnt += sp ? 1u : 0u;
            v = sp ? 0.0f : v;
        }
        __builtin_amdgcn_s_waitcnt(0);           // reads done before next nt overwrites
    }
    atomicAdd(&pool[b * C2_ + c2v], (float)cnt);  // integer-valued: exact, order-free
}

// ---------------- K3: fc on pooled [B][C2] (pool already summed over l,t) ----------------
__global__ __launch_bounds__(128) void k3_fc(const float* __restrict__ pool,
                                             const float* __restrict__ fcw,
                                             const float* __restrict__ fcb,
                                             float* __restrict__ out) {
    int i = threadIdx.x;          // 128 = B*4 outputs
    int b = i >> 2, c = i & 3;
    float o = fcb[c];
    #pragma unroll 8
    for (int c2 = 0; c2 < C2_; ++c2)
        o = fmaf(fcw[c * C2_ + c2], pool[b * C2_ + c2] * (1.0f / 65536.0f), o);
    out[b * 4 + c] = o;
}

extern "C" void kernel_launch(void* const* d_in, const int* in_sizes, int n_in,
                              void* d_out, int out_size, void* d_ws, size_t ws_size,
                              hipStream_t stream) {
    const float* x   = (const float*)d_in[0];
    const float* w1  = (const float*)d_in[1];
    const float* b1  = (const float*)d_in[2];
    const float* w2  = (const float*)d_in[3];
    const float* b2  = (const float*)d_in[4];
    const float* fcw = (const float*)d_in[5];
    const float* fcb = (const float*)d_in[6];
    float* out = (float*)d_out;

    char* ws = (char*)d_ws;
    ushort* s1t  = (ushort*)(ws + WS_S1T);
    ushort* w2h  = (ushort*)(ws + WS_W2HI);
    ushort* w1f  = (ushort*)(ws + WS_W1F);
    float*  pool = (float*)(ws + WS_POOL);
    ushort* zp   = (ushort*)(ws + WS_ZP);

    k0_prep_w2<<<dim3((C2_ * K_ * C1_ + 255) / 256), dim3(256), 0, stream>>>(w2, w2h, pool, zp);
    k0_prep_w1<<<dim3(64), dim3(256), 0, stream>>>(w1, w1f);
    k1_conv1_mfma<<<dim3(L_ / 4, B_), dim3(256), 0, stream>>>(x, w1f, b1, s1t);
    k2_conv2_lif<<<dim3(L_ / 4, B_), dim3(512), 81920, stream>>>(s1t, w2h, b2, pool, zp);
    k3_fc<<<dim3(1), dim3(128), 0, stream>>>(pool, fcw, fcb, out);
}